// Round 5
// baseline (1312.434 us; speedup 1.0000x reference)
//
#include <hip/hip_runtime.h>
#include <hip/hip_bf16.h>

#define V_ 100000
#define E_ 100
#define H_ 100
#define T_ 25
#define B_ 256
#define S_ 512

using u16 = unsigned short;
using u32 = unsigned int;
using u64 = unsigned long long;
typedef __attribute__((ext_vector_type(8))) short short8;
typedef __attribute__((ext_vector_type(4))) float f32x4;

__device__ __forceinline__ float bf2f(u16 v){
  u32 x = ((u32)v) << 16;
  return __builtin_bit_cast(float, x);
}
__device__ __forceinline__ u16 f2bf(float f){
  u32 x = __builtin_bit_cast(u32, f);
  u32 r = (x + 0x7FFFu + ((x >> 16) & 1u)) >> 16;  // RNE
  return (u16)r;
}
__device__ __forceinline__ float sigf(float x){
  return 1.0f / (1.0f + __builtin_amdgcn_exp2f(-1.4426950408889634f * x));
}
__device__ __forceinline__ float tanh_fast(float x){
  return 1.0f - 2.0f / (1.0f + __builtin_amdgcn_exp2f(2.8853900817779268f * x));
}
__device__ __forceinline__ float bcast(float v, int l){
  return __builtin_bit_cast(float, __builtin_amdgcn_readlane(__builtin_bit_cast(int, v), l));
}
// 256B-row XOR swizzle: byte ^= ((row&7)<<4); involution, preserves 16B chunks
__device__ __forceinline__ int hswz(int a){ return a ^ (((a >> 8) & 7) << 4); }

__device__ __forceinline__ void gl_lds16(const void* g, void* l){
  __builtin_amdgcn_global_load_lds(
      (const __attribute__((address_space(1))) unsigned int*)g,
      (__attribute__((address_space(3))) unsigned int*)l, 16, 0, 0);
}

// LDS-visibility-only barrier (no vmcnt drain)
#define BAR() asm volatile("s_waitcnt lgkmcnt(0)\n\ts_barrier" ::: "memory")

// ---------------------------------------------------------------------------
// prep: xg gather/cvt (blocks 0..16383) + wpad build (blocks 16384..17279).
// xg[s*256+b][128] bf16 = embed row (zero-padded k>=100).
// wpad[dir][448][256] bf16: rows g*112+j; cols 0..99 = w_ih, 128..227 = w_hh.
// ---------------------------------------------------------------------------
__global__ __launch_bounds__(256) void prep_kernel(
    const int* __restrict__ sent, const float* __restrict__ tab,
    const float* __restrict__ w_ih_f, const float* __restrict__ w_hh_f,
    const float* __restrict__ w_ih_b, const float* __restrict__ w_hh_b,
    u16* __restrict__ xg, u16* __restrict__ wpad)
{
  int bid = blockIdx.x;
  if (bid < 16384){
    int tid = bid * 256 + threadIdx.x;      // 131072*32
    int srow = tid >> 5, kb = tid & 31;
    int s = srow >> 8, b = srow & 255;
    int k0 = kb * 4;
    u64 out = 0;
    if (k0 < 100){
      int idx = sent[b * S_ + s];
      float4 v = *(const float4*)(tab + (size_t)idx * 100 + k0);
      out = (u64)f2bf(v.x) | ((u64)f2bf(v.y) << 16)
          | ((u64)f2bf(v.z) << 32) | ((u64)f2bf(v.w) << 48);
    }
    ((u64*)xg)[tid] = out;
  } else {
    int tid = (bid - 16384) * 256 + threadIdx.x;   // 2*448*256
    int dir = tid / (448 * 256);
    int rem = tid % (448 * 256);
    int np = rem >> 8, k = rem & 255;
    int g = np / 112, j = np % 112;
    float v = 0.f;
    if (j < 100){
      int n = g * 100 + j;
      if (k < 100)                    v = (dir ? w_ih_b : w_ih_f)[n * 100 + k];
      else if (k >= 128 && k < 228)   v = (dir ? w_hh_b : w_hh_f)[n * 100 + (k - 128)];
    }
    wpad[tid] = f2bf(v);
  }
}

// ---------------------------------------------------------------------------
// Fused LSTM. block = (bb 16-batch group, dir), 448 thr = 7 waves.
// gates^T = Wpad[448][256] . [x;h][256][16] via mfma_16x16x32_bf16 (A=W).
// x staged in LDS by global_load_lds (4KB/step, shared by all waves), 3-deep
// prefetch, counted vmcnt(2) at step end (loads/stores stay in flight).
// h double-buffered in swizzled LDS; nonlinearity fully in-register.
// ---------------------------------------------------------------------------
__global__ __launch_bounds__(448, 1) void lstm_kernel(
    const u16* __restrict__ xg, const u16* __restrict__ wpad,
    const float* __restrict__ b_ih_f, const float* __restrict__ b_hh_f,
    const float* __restrict__ b_ih_b, const float* __restrict__ b_hh_b,
    u16* __restrict__ hbuf)
{
  int bb = blockIdx.x, dir = blockIdx.y;
  int t = threadIdx.x, w = t >> 6, l = t & 63;
  int m = l & 15, ql = l >> 4;
  int j0 = w * 16 + ql * 4;
  bool jv = j0 < 100;

  __shared__ __align__(16) char ha[2][4096];   // h[16][128] bf16, swizzled
  __shared__ __align__(16) char xb[3][4096];   // x tiles, swizzled, 3-deep

  for (int i = t; i < 2048; i += 448) ((u32*)ha)[i] = 0;

  // loop-invariant W fragments (128 VGPR)
  short8 bf[4][8];
  {
    const u16* wb = wpad + (size_t)dir * 448 * 256;
#pragma unroll
    for (int g = 0; g < 4; g++)
#pragma unroll
      for (int ks = 0; ks < 8; ks++)
        bf[g][ks] = *(const short8*)(wb + (g * 112 + w * 16 + m) * 256 + ks * 32 + ql * 8);
  }
  // bias folded into MFMA C-init
  f32x4 bias4[4];
#pragma unroll
  for (int g = 0; g < 4; g++) bias4[g] = (f32x4){0.f, 0.f, 0.f, 0.f};
  if (jv){
    const float* bi = dir ? b_ih_b : b_ih_f;
    const float* bh = dir ? b_hh_b : b_hh_f;
#pragma unroll
    for (int g = 0; g < 4; g++)
#pragma unroll
      for (int r = 0; r < 4; r++)
        bias4[g][r] = bi[g * 100 + j0 + r] + bh[g * 100 + j0 + r];
  }

  float c[4] = {0.f, 0.f, 0.f, 0.f};
  int s0 = dir ? (S_ - 1) : 0, sd = dir ? -1 : 1;

  // prologue: stage x for steps 0 and 1
  {
    if (t < 256){
      int sp0 = s0;
      int sp1 = s0 + sd;
      const char* src0 = (const char*)xg + ((size_t)(sp0 * B_ + bb * 16)) * 256;
      const char* src1 = (const char*)xg + ((size_t)(sp1 * B_ + bb * 16)) * 256;
      gl_lds16(src0 + hswz(t * 16), xb[0] + w * 1024);
      gl_lds16(src1 + hswz(t * 16), xb[1] + w * 1024);
    }
  }
  asm volatile("s_waitcnt vmcnt(1)" ::: "memory");
  __syncthreads();

  u16* hout = hbuf + ((size_t)(s0 * B_ + bb * 16 + m)) * 200 + dir * 100 + j0;
  const long hstride = (long)sd * B_ * 200;

  for (int k = 0; k < S_; ++k){
    // stage x for step k+2 (buffer (k+2)%3 was consumed at step k-1)
    if (t < 256){
      int kk = k + 2; if (kk > S_ - 1) kk = S_ - 1;
      int sp = s0 + sd * kk;
      const char* src = (const char*)xg + ((size_t)(sp * B_ + bb * 16)) * 256;
      gl_lds16(src + hswz(t * 16), xb[(k + 2) % 3] + w * 1024);
    }

    const char* xp = xb[k % 3];
    const char* hp = ha[(k & 1) ^ 1];
    short8 xf[4], hf[4];
#pragma unroll
    for (int ks = 0; ks < 4; ks++){
      int off = m * 256 + ks * 64 + ql * 16;
      xf[ks] = *(const short8*)(xp + hswz(off));
      hf[ks] = *(const short8*)(hp + hswz(off));
    }

    f32x4 acc[4];
    // x-chains first (independent of h-read latency)
#pragma unroll
    for (int g = 0; g < 4; g++){
      acc[g] = __builtin_amdgcn_mfma_f32_16x16x32_bf16(bf[g][0], xf[0], bias4[g], 0, 0, 0);
#pragma unroll
      for (int ks = 1; ks < 4; ks++)
        acc[g] = __builtin_amdgcn_mfma_f32_16x16x32_bf16(bf[g][ks], xf[ks], acc[g], 0, 0, 0);
    }
#pragma unroll
    for (int g = 0; g < 4; g++)
#pragma unroll
      for (int ks = 0; ks < 4; ks++)
        acc[g] = __builtin_amdgcn_mfma_f32_16x16x32_bf16(bf[g][4 + ks], hf[ks], acc[g], 0, 0, 0);

    if (jv){
      u64 pk = 0;
#pragma unroll
      for (int r = 0; r < 4; r++){
        float gi = sigf(acc[0][r]);
        float gf = sigf(acc[1][r]);
        float gg = tanh_fast(acc[2][r]);
        float go = sigf(acc[3][r]);
        c[r] = gf * c[r] + gi * gg;
        float h = go * tanh_fast(c[r]);
        pk |= ((u64)f2bf(h)) << (16 * r);
      }
      *(u64*)(ha[k & 1] + hswz(m * 256 + j0 * 2)) = pk;   // next-step h
      *(u64*)hout = pk;                                    // persist
    }
    hout += hstride;

    // force x[k+1] DMA complete (allow newest DMA + own store in flight)
    asm volatile("s_waitcnt vmcnt(2)" ::: "memory");
    BAR();
  }
}

// ---------------------------------------------------------------------------
// emissions = [hf,hb] @ w_out^T + b_out.  w_out staged in LDS.
// ---------------------------------------------------------------------------
__global__ __launch_bounds__(256) void emis_kernel(
    const u16* __restrict__ hbuf, const float* __restrict__ w_out,
    const float* __restrict__ b_out, float* __restrict__ em)
{
  __shared__ float wsm[T_ * 200];
  int t = threadIdx.x;
  for (int i = t; i < T_ * 200; i += 256) wsm[i] = w_out[i];
  __syncthreads();

  int tid = blockIdx.x * 256 + t;   // s*B + b
  uint4 hr[25];
  const uint4* hp = (const uint4*)(hbuf + (size_t)tid * 200);
#pragma unroll
  for (int i = 0; i < 25; i++) hr[i] = hp[i];
  float* out = em + (size_t)tid * T_;
  for (int tt = 0; tt < T_; ++tt){
    const float* wr = wsm + tt * 200;
    float acc = b_out[tt];
#pragma unroll
    for (int i = 0; i < 25; i++){
      u32 q0 = hr[i].x, q1 = hr[i].y, q2 = hr[i].z, q3 = hr[i].w;
      float f;
      f = __builtin_bit_cast(float, q0 << 16);         acc += f * wr[i*8+0];
      f = __builtin_bit_cast(float, q0 & 0xFFFF0000u); acc += f * wr[i*8+1];
      f = __builtin_bit_cast(float, q1 << 16);         acc += f * wr[i*8+2];
      f = __builtin_bit_cast(float, q1 & 0xFFFF0000u); acc += f * wr[i*8+3];
      f = __builtin_bit_cast(float, q2 << 16);         acc += f * wr[i*8+4];
      f = __builtin_bit_cast(float, q2 & 0xFFFF0000u); acc += f * wr[i*8+5];
      f = __builtin_bit_cast(float, q3 << 16);         acc += f * wr[i*8+6];
      f = __builtin_bit_cast(float, q3 & 0xFFFF0000u); acc += f * wr[i*8+7];
    }
    out[tt] = acc;
  }
}

// ---------------------------------------------------------------------------
// CRF: wave 0 = logZ scan (trans column in VGPRs), wave 1 = gold score.
// diff[b] = logZ[b] - num[b].
// ---------------------------------------------------------------------------
__global__ __launch_bounds__(128) void logznum_kernel(
    const float* __restrict__ em, const int* __restrict__ tags,
    const float* __restrict__ start_t, const float* __restrict__ end_t,
    const float* __restrict__ trans, float* __restrict__ diff)
{
  int b = blockIdx.x, t = threadIdx.x;
  __shared__ float tr_s[T_ * T_];
  __shared__ float res[2];
  for (int i = t; i < T_ * T_; i += 128) tr_s[i] = trans[i];
  __syncthreads();

  if (t < 64){
    int lane = t;
    bool act = lane < T_;
    int ll = act ? lane : 0;
    float trc[T_];
#pragma unroll
    for (int tt = 0; tt < T_; tt++) trc[tt] = tr_s[tt * T_ + ll];
    float score = act ? (start_t[ll] + em[(size_t)b * T_ + ll]) : -1e30f;
    float e_next = em[((size_t)1 * B_ + b) * T_ + ll];
    for (int s = 1; s < S_; ++s){
      float e = e_next;
      int sn = (s + 1 < S_) ? s + 1 : S_ - 1;
      e_next = em[((size_t)sn * B_ + b) * T_ + ll];
      float v[T_];
#pragma unroll
      for (int tt = 0; tt < T_; tt++)
        v[tt] = bcast(score, tt) + trc[tt];
      float mx[T_];
#pragma unroll
      for (int tt = 0; tt < T_; tt++) mx[tt] = v[tt];
#pragma unroll
      for (int n = T_; n > 1; ){
        int h = (n + 1) >> 1;
#pragma unroll
        for (int i = 0; i < T_ / 2; i++)
          if (i + h < n) mx[i] = fmaxf(mx[i], mx[i + h]);
        n = h;
      }
      float m = mx[0];
      float ex[T_];
#pragma unroll
      for (int tt = 0; tt < T_; tt++)
        ex[tt] = __builtin_amdgcn_exp2f(1.4426950408889634f * (v[tt] - m));
#pragma unroll
      for (int n = T_; n > 1; ){
        int h = (n + 1) >> 1;
#pragma unroll
        for (int i = 0; i < T_ / 2; i++)
          if (i + h < n) ex[i] += ex[i + h];
        n = h;
      }
      float nxt = m + 0.69314718055994531f * __builtin_amdgcn_logf(ex[0]) + e;
      score = act ? nxt : -1e30f;
    }
    float val = act ? (score + end_t[ll]) : -1e30f;
    float m = val;
    for (int off = 32; off; off >>= 1) m = fmaxf(m, __shfl_xor(m, off));
    float sum = __builtin_amdgcn_exp2f(1.4426950408889634f * (val - m));
    for (int off = 32; off; off >>= 1) sum += __shfl_xor(sum, off);
    if (lane == 0) res[0] = m + 0.69314718055994531f * __builtin_amdgcn_logf(sum);
  } else {
    int lane = t - 64;
    float acc = 0.f;
    for (int s = 1 + lane; s < S_; s += 64){
      int tp = tags[b * S_ + s - 1], tc = tags[b * S_ + s];
      acc += tr_s[tp * T_ + tc] + em[((size_t)s * B_ + b) * T_ + tc];
    }
    if (lane == 0){
      int t0 = tags[b * S_];
      acc += start_t[t0] + em[(size_t)b * T_ + t0] + end_t[tags[b * S_ + S_ - 1]];
    }
    for (int off = 32; off; off >>= 1) acc += __shfl_xor(acc, off);
    if (lane == 0) res[1] = acc;
  }
  __syncthreads();
  if (t == 0) diff[b] = res[0] - res[1];
}

// ---------------------------------------------------------------------------
__global__ __launch_bounds__(256) void final_kernel(
    const float* __restrict__ diff, float* __restrict__ out)
{
  int t = threadIdx.x;
  float v = diff[t];
  __shared__ float red[4];
  for (int off = 32; off; off >>= 1) v += __shfl_xor(v, off);
  if ((t & 63) == 0) red[t >> 6] = v;
  __syncthreads();
  if (t == 0) out[0] = red[0] + red[1] + red[2] + red[3];
}

extern "C" void kernel_launch(void* const* d_in, const int* in_sizes, int n_in,
                              void* d_out, int out_size, void* d_ws, size_t ws_size,
                              hipStream_t stream) {
  const int*   sent    = (const int*)  d_in[0];
  const int*   tags    = (const int*)  d_in[1];
  const float* tab     = (const float*)d_in[3];
  const float* w_ih_f  = (const float*)d_in[4];
  const float* w_hh_f  = (const float*)d_in[5];
  const float* b_ih_f  = (const float*)d_in[6];
  const float* b_hh_f  = (const float*)d_in[7];
  const float* w_ih_b  = (const float*)d_in[8];
  const float* w_hh_b  = (const float*)d_in[9];
  const float* b_ih_b  = (const float*)d_in[10];
  const float* b_hh_b  = (const float*)d_in[11];
  const float* w_out   = (const float*)d_in[12];
  const float* b_out   = (const float*)d_in[13];
  const float* start_t = (const float*)d_in[14];
  const float* end_t   = (const float*)d_in[15];
  const float* trans   = (const float*)d_in[16];

  // Workspace (~100 MB)
  char* ws = (char*)d_ws;
  u16*   hbuf = (u16*)ws;                          // 52,428,800 B
  float* em   = (float*)(ws + 52428800);           // 13,107,200 B
  float* diff = (float*)(ws + 65536000);           //      1,024 B
  u16*   wpad = (u16*)(ws + 65538048);             //    458,752 B
  u16*   xg   = (u16*)(ws + 65996800);             // 33,554,432 B

  prep_kernel<<<17280, 256, 0, stream>>>(sent, tab, w_ih_f, w_hh_f,
                                         w_ih_b, w_hh_b, xg, wpad);
  lstm_kernel<<<dim3(16, 2), 448, 0, stream>>>(xg, wpad,
      b_ih_f, b_hh_f, b_ih_b, b_hh_b, hbuf);
  emis_kernel<<<512, 256, 0, stream>>>(hbuf, w_out, b_out, em);
  logznum_kernel<<<256, 128, 0, stream>>>(em, tags, start_t, end_t, trans, diff);
  final_kernel<<<1, 256, 0, stream>>>(diff, (float*)d_out);
}

// Round 6
// 890.881 us; speedup vs baseline: 1.4732x; 1.4732x over previous
//
#include <hip/hip_runtime.h>
#include <hip/hip_bf16.h>

#define V_ 100000
#define E_ 100
#define H_ 100
#define T_ 25
#define B_ 256
#define S_ 512

using u16 = unsigned short;
using u32 = unsigned int;
using u64 = unsigned long long;
typedef __attribute__((ext_vector_type(8))) short short8;
typedef __attribute__((ext_vector_type(4))) float f32x4;

__device__ __forceinline__ float bf2f(u16 v){
  u32 x = ((u32)v) << 16;
  return __builtin_bit_cast(float, x);
}
__device__ __forceinline__ u16 f2bf(float f){
  u32 x = __builtin_bit_cast(u32, f);
  u32 r = (x + 0x7FFFu + ((x >> 16) & 1u)) >> 16;  // RNE
  return (u16)r;
}
__device__ __forceinline__ float sigf(float x){
  return __builtin_amdgcn_rcpf(1.0f + __builtin_amdgcn_exp2f(-1.4426950408889634f * x));
}
__device__ __forceinline__ float tanh_fast(float x){
  return 1.0f - 2.0f * __builtin_amdgcn_rcpf(1.0f + __builtin_amdgcn_exp2f(2.8853900817779268f * x));
}
__device__ __forceinline__ float bcast(float v, int l){
  return __builtin_bit_cast(float, __builtin_amdgcn_readlane(__builtin_bit_cast(int, v), l));
}
// 256B-row XOR swizzle: byte ^= ((row&7)<<4); involution, preserves 16B chunks
__device__ __forceinline__ int hswz(int a){ return a ^ (((a >> 8) & 7) << 4); }

// LDS-visibility-only barrier (no vmcnt drain)
#define BAR() asm volatile("s_waitcnt lgkmcnt(0)\n\ts_barrier" ::: "memory")

// ---------------------------------------------------------------------------
// prep: xg gather/cvt (blocks 0..16383) + wpad build (blocks 16384..17279).
// xg[s*256+b][128] bf16 = embed row (zero-padded k>=100).
// wpad[dir][448][256] bf16: rows g*112+j; cols 0..99 = w_ih, 128..227 = w_hh.
// ---------------------------------------------------------------------------
__global__ __launch_bounds__(256) void prep_kernel(
    const int* __restrict__ sent, const float* __restrict__ tab,
    const float* __restrict__ w_ih_f, const float* __restrict__ w_hh_f,
    const float* __restrict__ w_ih_b, const float* __restrict__ w_hh_b,
    u16* __restrict__ xg, u16* __restrict__ wpad)
{
  int bid = blockIdx.x;
  if (bid < 16384){
    int tid = bid * 256 + threadIdx.x;      // 131072*32
    int srow = tid >> 5, kb = tid & 31;
    int s = srow >> 8, b = srow & 255;
    int k0 = kb * 4;
    u64 out = 0;
    if (k0 < 100){
      int idx = sent[b * S_ + s];
      float4 v = *(const float4*)(tab + (size_t)idx * 100 + k0);
      out = (u64)f2bf(v.x) | ((u64)f2bf(v.y) << 16)
          | ((u64)f2bf(v.z) << 32) | ((u64)f2bf(v.w) << 48);
    }
    ((u64*)xg)[tid] = out;
  } else {
    int tid = (bid - 16384) * 256 + threadIdx.x;   // 2*448*256
    int dir = tid / (448 * 256);
    int rem = tid % (448 * 256);
    int np = rem >> 8, k = rem & 255;
    int g = np / 112, j = np % 112;
    float v = 0.f;
    if (j < 100){
      int n = g * 100 + j;
      if (k < 100)                    v = (dir ? w_ih_b : w_ih_f)[n * 100 + k];
      else if (k >= 128 && k < 228)   v = (dir ? w_hh_b : w_hh_f)[n * 100 + (k - 128)];
    }
    wpad[tid] = f2bf(v);
  }
}

// ---------------------------------------------------------------------------
// Fused LSTM. block = (bb 16-batch group, dir), 448 thr = 7 waves.
// gates^T = Wpad[448][256] . [x;h][256][16] via mfma_16x16x32_bf16 (A=W).
// Pipelined: acc(k+1) = bias + Wx.x(k+1) computed AFTER nonlin(k), BEFORE the
// barrier (overlaps barrier wait); post-barrier path is only the 4-deep
// h-MFMA chains + nonlin. x per-lane register prefetch (no LDS, no manual
// vmcnt). h double-buffered in 8KB swizzled LDS.
// ---------------------------------------------------------------------------
__global__ __launch_bounds__(448, 1) void lstm_kernel(
    const u16* __restrict__ xg, const u16* __restrict__ wpad,
    const float* __restrict__ b_ih_f, const float* __restrict__ b_hh_f,
    const float* __restrict__ b_ih_b, const float* __restrict__ b_hh_b,
    u16* __restrict__ hbuf)
{
  int bb = blockIdx.x, dir = blockIdx.y;
  int t = threadIdx.x, w = t >> 6, l = t & 63;
  int m = l & 15, ql = l >> 4;
  int j0 = w * 16 + ql * 4;
  bool jv = j0 < 100;

  __shared__ __align__(16) char ha[2][4096];   // h[16][128] bf16, swizzled

  for (int i = t; i < 2048; i += 448) ((u32*)ha)[i] = 0;

  // loop-invariant W fragments (live in AGPR half of the unified file)
  short8 bf[4][8];
  {
    const u16* wb = wpad + (size_t)dir * 448 * 256;
#pragma unroll
    for (int g = 0; g < 4; g++)
#pragma unroll
      for (int ks = 0; ks < 8; ks++)
        bf[g][ks] = *(const short8*)(wb + (g * 112 + w * 16 + m) * 256 + ks * 32 + ql * 8);
  }
  // bias folded into MFMA C-init
  f32x4 bias4[4];
#pragma unroll
  for (int g = 0; g < 4; g++) bias4[g] = (f32x4){0.f, 0.f, 0.f, 0.f};
  if (jv){
    const float* bi = dir ? b_ih_b : b_ih_f;
    const float* bh = dir ? b_hh_b : b_hh_f;
#pragma unroll
    for (int g = 0; g < 4; g++)
#pragma unroll
      for (int r = 0; r < 4; r++)
        bias4[g][r] = bi[g * 100 + j0 + r] + bh[g * 100 + j0 + r];
  }

  float c[4] = {0.f, 0.f, 0.f, 0.f};
  int s0 = dir ? (S_ - 1) : 0, sd = dir ? -1 : 1;

  const u16* xbase = xg + ((size_t)(bb * 16 + m)) * 128 + ql * 8;
  const int XSTRIDE = 256 * 128;                 // elems per s

  // prologue: x(0), x(1) in regs; accA = bias + Wx.x(0)
  short8 xc0[4], xc1[4];
#pragma unroll
  for (int ks = 0; ks < 4; ks++){
    xc0[ks] = *(const short8*)(xbase + (size_t)s0 * XSTRIDE + ks * 32);
    xc1[ks] = *(const short8*)(xbase + (size_t)(s0 + sd) * XSTRIDE + ks * 32);
  }
  f32x4 accA[4], accB[4];
#pragma unroll
  for (int g = 0; g < 4; g++){
    accA[g] = __builtin_amdgcn_mfma_f32_16x16x32_bf16(bf[g][0], xc0[0], bias4[g], 0, 0, 0);
#pragma unroll
    for (int ks = 1; ks < 4; ks++)
      accA[g] = __builtin_amdgcn_mfma_f32_16x16x32_bf16(bf[g][ks], xc0[ks], accA[g], 0, 0, 0);
  }

  u16* hout = hbuf + ((size_t)(s0 * B_ + bb * 16 + m)) * 200 + dir * 100 + j0;
  const long hstride = (long)sd * B_ * 200;
  int kcur = 0;

  __syncthreads();

  // Step body: ACC holds bias+Wx.x(kcur); XN = x(kcur+1) frags; XL gets x(kcur+2);
  // AOUT = bias+Wx.x(kcur+1) for next step.  KODD = kcur&1 (static).
#define STEP(KODD, ACC, XN, AOUT, XL) do {                                     \
    const char* hp_ = ha[(KODD) ^ 1];                                          \
    short8 hf_[4];                                                             \
    _Pragma("unroll")                                                          \
    for (int ks = 0; ks < 4; ks++)                                             \
      hf_[ks] = *(const short8*)(hp_ + hswz(m * 256 + ks * 64 + ql * 16));     \
    _Pragma("unroll")                                                          \
    for (int g = 0; g < 4; g++)                                                \
      _Pragma("unroll")                                                        \
      for (int ks = 0; ks < 4; ks++)                                           \
        ACC[g] = __builtin_amdgcn_mfma_f32_16x16x32_bf16(bf[g][4 + ks], hf_[ks], ACC[g], 0, 0, 0); \
    { int kk = kcur + 2; if (kk > S_ - 1) kk = S_ - 1;                         \
      const u16* xp_ = xbase + (size_t)(s0 + sd * kk) * XSTRIDE;               \
      _Pragma("unroll")                                                        \
      for (int ks = 0; ks < 4; ks++) XL[ks] = *(const short8*)(xp_ + ks * 32); }\
    if (jv){                                                                   \
      u64 pk = 0;                                                              \
      _Pragma("unroll")                                                        \
      for (int r = 0; r < 4; r++){                                             \
        float gi = sigf(ACC[0][r]);                                            \
        float gf = sigf(ACC[1][r]);                                            \
        float gg = tanh_fast(ACC[2][r]);                                       \
        float go = sigf(ACC[3][r]);                                            \
        c[r] = gf * c[r] + gi * gg;                                            \
        float h = go * tanh_fast(c[r]);                                        \
        pk |= ((u64)f2bf(h)) << (16 * r);                                      \
      }                                                                        \
      *(u64*)(ha[KODD] + hswz(m * 256 + j0 * 2)) = pk;                         \
      *(u64*)hout = pk;                                                        \
    }                                                                          \
    hout += hstride;                                                           \
    _Pragma("unroll")                                                          \
    for (int g = 0; g < 4; g++){                                               \
      AOUT[g] = __builtin_amdgcn_mfma_f32_16x16x32_bf16(bf[g][0], XN[0], bias4[g], 0, 0, 0); \
      _Pragma("unroll")                                                        \
      for (int ks = 1; ks < 4; ks++)                                           \
        AOUT[g] = __builtin_amdgcn_mfma_f32_16x16x32_bf16(bf[g][ks], XN[ks], AOUT[g], 0, 0, 0); \
    }                                                                          \
    BAR();                                                                     \
    kcur++;                                                                    \
  } while (0)

  for (int it = 0; it < S_ / 2; ++it){
    STEP(0, accA, xc1, accB, xc0);
    STEP(1, accB, xc0, accA, xc1);
  }
#undef STEP
}

// ---------------------------------------------------------------------------
// emissions = [hf,hb] @ w_out^T + b_out.  w_out staged in LDS.
// ---------------------------------------------------------------------------
__global__ __launch_bounds__(256) void emis_kernel(
    const u16* __restrict__ hbuf, const float* __restrict__ w_out,
    const float* __restrict__ b_out, float* __restrict__ em)
{
  __shared__ float wsm[T_ * 200];
  int t = threadIdx.x;
  for (int i = t; i < T_ * 200; i += 256) wsm[i] = w_out[i];
  __syncthreads();

  int tid = blockIdx.x * 256 + t;   // s*B + b
  uint4 hr[25];
  const uint4* hp = (const uint4*)(hbuf + (size_t)tid * 200);
#pragma unroll
  for (int i = 0; i < 25; i++) hr[i] = hp[i];
  float* out = em + (size_t)tid * T_;
  for (int tt = 0; tt < T_; ++tt){
    const float* wr = wsm + tt * 200;
    float acc = b_out[tt];
#pragma unroll
    for (int i = 0; i < 25; i++){
      u32 q0 = hr[i].x, q1 = hr[i].y, q2 = hr[i].z, q3 = hr[i].w;
      float f;
      f = __builtin_bit_cast(float, q0 << 16);         acc += f * wr[i*8+0];
      f = __builtin_bit_cast(float, q0 & 0xFFFF0000u); acc += f * wr[i*8+1];
      f = __builtin_bit_cast(float, q1 << 16);         acc += f * wr[i*8+2];
      f = __builtin_bit_cast(float, q1 & 0xFFFF0000u); acc += f * wr[i*8+3];
      f = __builtin_bit_cast(float, q2 << 16);         acc += f * wr[i*8+4];
      f = __builtin_bit_cast(float, q2 & 0xFFFF0000u); acc += f * wr[i*8+5];
      f = __builtin_bit_cast(float, q3 << 16);         acc += f * wr[i*8+6];
      f = __builtin_bit_cast(float, q3 & 0xFFFF0000u); acc += f * wr[i*8+7];
    }
    out[tt] = acc;
  }
}

// ---------------------------------------------------------------------------
// CRF: wave 0 = logZ scan (trans column in VGPRs), wave 1 = gold score.
// diff[b] = logZ[b] - num[b].
// ---------------------------------------------------------------------------
__global__ __launch_bounds__(128) void logznum_kernel(
    const float* __restrict__ em, const int* __restrict__ tags,
    const float* __restrict__ start_t, const float* __restrict__ end_t,
    const float* __restrict__ trans, float* __restrict__ diff)
{
  int b = blockIdx.x, t = threadIdx.x;
  __shared__ float tr_s[T_ * T_];
  __shared__ float res[2];
  for (int i = t; i < T_ * T_; i += 128) tr_s[i] = trans[i];
  __syncthreads();

  if (t < 64){
    int lane = t;
    bool act = lane < T_;
    int ll = act ? lane : 0;
    float trc[T_];
#pragma unroll
    for (int tt = 0; tt < T_; tt++) trc[tt] = tr_s[tt * T_ + ll];
    float score = act ? (start_t[ll] + em[(size_t)b * T_ + ll]) : -1e30f;
    float e_next = em[((size_t)1 * B_ + b) * T_ + ll];
    for (int s = 1; s < S_; ++s){
      float e = e_next;
      int sn = (s + 1 < S_) ? s + 1 : S_ - 1;
      e_next = em[((size_t)sn * B_ + b) * T_ + ll];
      float v[T_];
#pragma unroll
      for (int tt = 0; tt < T_; tt++)
        v[tt] = bcast(score, tt) + trc[tt];
      float mx[T_];
#pragma unroll
      for (int tt = 0; tt < T_; tt++) mx[tt] = v[tt];
#pragma unroll
      for (int n = T_; n > 1; ){
        int h = (n + 1) >> 1;
#pragma unroll
        for (int i = 0; i < T_ / 2; i++)
          if (i + h < n) mx[i] = fmaxf(mx[i], mx[i + h]);
        n = h;
      }
      float m = mx[0];
      float ex[T_];
#pragma unroll
      for (int tt = 0; tt < T_; tt++)
        ex[tt] = __builtin_amdgcn_exp2f(1.4426950408889634f * (v[tt] - m));
#pragma unroll
      for (int n = T_; n > 1; ){
        int h = (n + 1) >> 1;
#pragma unroll
        for (int i = 0; i < T_ / 2; i++)
          if (i + h < n) ex[i] += ex[i + h];
        n = h;
      }
      float nxt = m + 0.69314718055994531f * __builtin_amdgcn_logf(ex[0]) + e;
      score = act ? nxt : -1e30f;
    }
    float val = act ? (score + end_t[ll]) : -1e30f;
    float m = val;
    for (int off = 32; off; off >>= 1) m = fmaxf(m, __shfl_xor(m, off));
    float sum = __builtin_amdgcn_exp2f(1.4426950408889634f * (val - m));
    for (int off = 32; off; off >>= 1) sum += __shfl_xor(sum, off);
    if (lane == 0) res[0] = m + 0.69314718055994531f * __builtin_amdgcn_logf(sum);
  } else {
    int lane = t - 64;
    float acc = 0.f;
    for (int s = 1 + lane; s < S_; s += 64){
      int tp = tags[b * S_ + s - 1], tc = tags[b * S_ + s];
      acc += tr_s[tp * T_ + tc] + em[((size_t)s * B_ + b) * T_ + tc];
    }
    if (lane == 0){
      int t0 = tags[b * S_];
      acc += start_t[t0] + em[(size_t)b * T_ + t0] + end_t[tags[b * S_ + S_ - 1]];
    }
    for (int off = 32; off; off >>= 1) acc += __shfl_xor(acc, off);
    if (lane == 0) res[1] = acc;
  }
  __syncthreads();
  if (t == 0) diff[b] = res[0] - res[1];
}

// ---------------------------------------------------------------------------
__global__ __launch_bounds__(256) void final_kernel(
    const float* __restrict__ diff, float* __restrict__ out)
{
  int t = threadIdx.x;
  float v = diff[t];
  __shared__ float red[4];
  for (int off = 32; off; off >>= 1) v += __shfl_xor(v, off);
  if ((t & 63) == 0) red[t >> 6] = v;
  __syncthreads();
  if (t == 0) out[0] = red[0] + red[1] + red[2] + red[3];
}

extern "C" void kernel_launch(void* const* d_in, const int* in_sizes, int n_in,
                              void* d_out, int out_size, void* d_ws, size_t ws_size,
                              hipStream_t stream) {
  const int*   sent    = (const int*)  d_in[0];
  const int*   tags    = (const int*)  d_in[1];
  const float* tab     = (const float*)d_in[3];
  const float* w_ih_f  = (const float*)d_in[4];
  const float* w_hh_f  = (const float*)d_in[5];
  const float* b_ih_f  = (const float*)d_in[6];
  const float* b_hh_f  = (const float*)d_in[7];
  const float* w_ih_b  = (const float*)d_in[8];
  const float* w_hh_b  = (const float*)d_in[9];
  const float* b_ih_b  = (const float*)d_in[10];
  const float* b_hh_b  = (const float*)d_in[11];
  const float* w_out   = (const float*)d_in[12];
  const float* b_out   = (const float*)d_in[13];
  const float* start_t = (const float*)d_in[14];
  const float* end_t   = (const float*)d_in[15];
  const float* trans   = (const float*)d_in[16];

  // Workspace (~100 MB)
  char* ws = (char*)d_ws;
  u16*   hbuf = (u16*)ws;                          // 52,428,800 B
  float* em   = (float*)(ws + 52428800);           // 13,107,200 B
  float* diff = (float*)(ws + 65536000);           //      1,024 B
  u16*   wpad = (u16*)(ws + 65538048);             //    458,752 B
  u16*   xg   = (u16*)(ws + 65996800);             // 33,554,432 B

  prep_kernel<<<17280, 256, 0, stream>>>(sent, tab, w_ih_f, w_hh_f,
                                         w_ih_b, w_hh_b, xg, wpad);
  lstm_kernel<<<dim3(16, 2), 448, 0, stream>>>(xg, wpad,
      b_ih_f, b_hh_f, b_ih_b, b_hh_b, hbuf);
  emis_kernel<<<512, 256, 0, stream>>>(hbuf, w_out, b_out, em);
  logznum_kernel<<<256, 128, 0, stream>>>(em, tags, start_t, end_t, trans, diff);
  final_kernel<<<1, 256, 0, stream>>>(diff, (float*)d_out);
}